// Round 2
// baseline (131.112 us; speedup 1.0000x reference)
//
#include <hip/hip_runtime.h>
#include <hip/hip_bf16.h>

// out[b,n] = prod_d psi((x[b,d]-c[n,d])/s[n,d]),  psi(z)=(1-z^2)exp(-z^2/2)
// Factorization: prod psi = [prod(1-z^2)] * exp(-0.5*sum z^2) per 16-d group
// (avoids fp32 overflow: |1-z^2|^16 ~ 1e30 < 3.4e38 for |z|<~9).
//
// R2 structure: d-streaming (d outer, n-chunk inner accumulators), fp32
// PACKED math via ext_vector_type(2) -> v_pk_fma_f32 (2x fp32 rate),
// transposed+packed params pp[dpair*N+n] = {cp0,cp1,rs0,rs1} so the inner
// loads are block-uniform s_load_dwordx16. NT=8 -> 2048 blocks, <=64 VGPR
// for 8 waves/SIMD.

#define DD 64
#define NT 8

typedef float v2f __attribute__((ext_vector_type(2)));

__global__ void prep_packed(const float* __restrict__ c,
                            const float* __restrict__ s,
                            float4* __restrict__ pp, int N) {
    int i = blockIdx.x * 256 + threadIdx.x;   // over N * (DD/2)
    int total = N * (DD / 2);
    if (i < total) {
        int dp = i / N, n = i - dp * N;
        int d = dp * 2;
        float r0 = 1.0f / s[n * DD + d];
        float r1 = 1.0f / s[n * DD + d + 1];
        pp[i] = make_float4(c[n * DD + d] * r0, c[n * DD + d + 1] * r1, r0, r1);
    }
}

__global__ __launch_bounds__(256, 8)
void wavelet_kernel(const float* __restrict__ x,
                    const float4* __restrict__ pp,
                    float* __restrict__ out, int B, int N) {
    int b = blockIdx.x * 256 + threadIdx.x;
    if (b >= B) return;
    int n0 = blockIdx.y * NT;
    const float4* pb = pp + n0;
    const float4* xv = (const float4*)(x + (size_t)b * DD);

    float acc[NT];
#pragma unroll
    for (int j = 0; j < NT; ++j) acc[j] = 1.0f;

#pragma unroll
    for (int g = 0; g < 4; ++g) {          // 4 groups of 16 d
        v2f p[NT], s2[NT];
#pragma unroll
        for (int j = 0; j < NT; ++j) {
            p[j]  = (v2f){1.0f, 1.0f};
            s2[j] = (v2f){0.0f, 0.0f};
        }
#pragma unroll
        for (int dq = 0; dq < 4; ++dq) {   // 4 float4's of x = 16 d
            float4 xq = xv[g * 4 + dq];
            v2f xa = {xq.x, xq.y};
            v2f xb2 = {xq.z, xq.w};
            const float4* rowa = pb + (size_t)(g * 8 + dq * 2) * N; // d-pair row
            const float4* rowb = rowa + N;
#pragma unroll
            for (int j = 0; j < NT; ++j) {
                float4 qa = rowa[j];                    // block-uniform -> s_load
                v2f cp = {qa.x, qa.y};
                v2f rs = {qa.z, qa.w};
                v2f z = __builtin_elementwise_fma(xa, rs, -cp);
                p[j] *= __builtin_elementwise_fma(-z, z, (v2f){1.0f, 1.0f});
                s2[j] = __builtin_elementwise_fma(z, z, s2[j]);
            }
#pragma unroll
            for (int j = 0; j < NT; ++j) {
                float4 qb = rowb[j];
                v2f cp = {qb.x, qb.y};
                v2f rs = {qb.z, qb.w};
                v2f z = __builtin_elementwise_fma(xb2, rs, -cp);
                p[j] *= __builtin_elementwise_fma(-z, z, (v2f){1.0f, 1.0f});
                s2[j] = __builtin_elementwise_fma(z, z, s2[j]);
            }
        }
#pragma unroll
        for (int j = 0; j < NT; ++j) {      // group boundary: one exp per 16 d
            float pr = p[j].x * p[j].y;
            float sr = s2[j].x + s2[j].y;
            acc[j] *= pr * __expf(-0.5f * sr);
        }
    }

    float4* op = (float4*)(out + (size_t)b * N + n0);
#pragma unroll
    for (int j = 0; j < NT / 4; ++j)
        op[j] = make_float4(acc[4 * j], acc[4 * j + 1],
                            acc[4 * j + 2], acc[4 * j + 3]);
}

extern "C" void kernel_launch(void* const* d_in, const int* in_sizes, int n_in,
                              void* d_out, int out_size, void* d_ws, size_t ws_size,
                              hipStream_t stream) {
    const float* x = (const float*)d_in[0];
    const float* c = (const float*)d_in[1];
    const float* s = (const float*)d_in[2];
    float* out = (float*)d_out;

    int B = in_sizes[0] / DD;    // 8192
    int N = in_sizes[1] / DD;    // 512

    float4* pp = (float4*)d_ws;  // N * 32 * 16 B = 256 KB

    int total = N * (DD / 2);
    prep_packed<<<(total + 255) / 256, 256, 0, stream>>>(c, s, pp, N);

    dim3 grid((B + 255) / 256, N / NT);
    wavelet_kernel<<<grid, 256, 0, stream>>>(x, pp, out, B, N);
}

// Round 3
// 97.744 us; speedup vs baseline: 1.3414x; 1.3414x over previous
//
#include <hip/hip_runtime.h>
#include <hip/hip_bf16.h>

// out[b,n] = prod_d psi((x[b,d]-c[n,d])/s[n,d]),  psi(z)=(1-z^2)exp(-z^2/2)
// Factorization: prod psi = [prod(1-z^2)] * exp(-0.5*sum z^2) per 16-d group
// (avoids fp32 overflow: |1-z^2|^16 ~ 1e30 < 3.4e38 for |z|<~9; data |z|<9).
//
// R3: same d-streaming + packed-fp32 structure as R2 but
// __launch_bounds__(256,4): R2's (256,8) forced VGPR=32 and spilled all
// accumulators to scratch (WRITE_SIZE 169 MB, 80 us). ~80 VGPRs needed.
// Inner step per element pair (v_pk_*): z=fma(x,rs,-cp); w=z*z;
// p=fma(-w,p,p); s2+=w  -> 4 pk-inst per 2 elements.

#define DD 64
#define NT 8

typedef float v2f __attribute__((ext_vector_type(2)));

__global__ void prep_packed(const float* __restrict__ c,
                            const float* __restrict__ s,
                            float4* __restrict__ pp, int N) {
    int i = blockIdx.x * 256 + threadIdx.x;   // over N * (DD/2)
    int total = N * (DD / 2);
    if (i < total) {
        int dp = i / N, n = i - dp * N;
        int d = dp * 2;
        float r0 = 1.0f / s[n * DD + d];
        float r1 = 1.0f / s[n * DD + d + 1];
        pp[i] = make_float4(c[n * DD + d] * r0, c[n * DD + d + 1] * r1, r0, r1);
    }
}

__global__ __launch_bounds__(256, 4)
void wavelet_kernel(const float* __restrict__ x,
                    const float4* __restrict__ pp,
                    float* __restrict__ out, int B, int N) {
    int b = blockIdx.x * 256 + threadIdx.x;
    if (b >= B) return;
    int n0 = blockIdx.y * NT;
    const float4* pb = pp + n0;
    const float4* xv = (const float4*)(x + (size_t)b * DD);

    float acc[NT];
#pragma unroll
    for (int j = 0; j < NT; ++j) acc[j] = 1.0f;

#pragma unroll
    for (int g = 0; g < 4; ++g) {          // 4 groups of 16 d
        v2f p[NT], s2[NT];
#pragma unroll
        for (int j = 0; j < NT; ++j) {
            p[j]  = (v2f){1.0f, 1.0f};
            s2[j] = (v2f){0.0f, 0.0f};
        }
#pragma unroll
        for (int dq = 0; dq < 4; ++dq) {   // 4 float4's of x = 16 d
            float4 xq = xv[g * 4 + dq];
            v2f xa = {xq.x, xq.y};
            v2f xb2 = {xq.z, xq.w};
            const float4* rowa = pb + (size_t)(g * 8 + dq * 2) * N; // d-pair row
            const float4* rowb = rowa + N;
#pragma unroll
            for (int j = 0; j < NT; ++j) {
                float4 qa = rowa[j];                    // block-uniform -> s_load
                v2f cp = {qa.x, qa.y};
                v2f rs = {qa.z, qa.w};
                v2f z = __builtin_elementwise_fma(xa, rs, -cp);
                v2f w = z * z;
                p[j] = __builtin_elementwise_fma(-w, p[j], p[j]);
                s2[j] += w;
            }
#pragma unroll
            for (int j = 0; j < NT; ++j) {
                float4 qb = rowb[j];
                v2f cp = {qb.x, qb.y};
                v2f rs = {qb.z, qb.w};
                v2f z = __builtin_elementwise_fma(xb2, rs, -cp);
                v2f w = z * z;
                p[j] = __builtin_elementwise_fma(-w, p[j], p[j]);
                s2[j] += w;
            }
        }
#pragma unroll
        for (int j = 0; j < NT; ++j) {      // group boundary: one exp per 16 d
            float pr = p[j].x * p[j].y;
            float sr = s2[j].x + s2[j].y;
            acc[j] *= pr * __expf(-0.5f * sr);
        }
    }

    float4* op = (float4*)(out + (size_t)b * N + n0);
#pragma unroll
    for (int j = 0; j < NT / 4; ++j)
        op[j] = make_float4(acc[4 * j], acc[4 * j + 1],
                            acc[4 * j + 2], acc[4 * j + 3]);
}

extern "C" void kernel_launch(void* const* d_in, const int* in_sizes, int n_in,
                              void* d_out, int out_size, void* d_ws, size_t ws_size,
                              hipStream_t stream) {
    const float* x = (const float*)d_in[0];
    const float* c = (const float*)d_in[1];
    const float* s = (const float*)d_in[2];
    float* out = (float*)d_out;

    int B = in_sizes[0] / DD;    // 8192
    int N = in_sizes[1] / DD;    // 512

    float4* pp = (float4*)d_ws;  // N * 32 * 16 B = 256 KB

    int total = N * (DD / 2);
    prep_packed<<<(total + 255) / 256, 256, 0, stream>>>(c, s, pp, N);

    dim3 grid((B + 255) / 256, N / NT);
    wavelet_kernel<<<grid, 256, 0, stream>>>(x, pp, out, B, N);
}